// Round 7
// baseline (122.543 us; speedup 1.0000x reference)
//
#include <hip/hip_runtime.h>

// Problem constants (x is [32,128,96,128] fp32)
#define BSZ 32
#define CC  128          // channels
#define CH  64           // C/2
#define HWN 12288        // 128*96 spatial positions
#define BPB 64           // blocks per batch for the streaming passes
#define ROWS (HWN/BPB)   // 192 rows per block

using f4 = __attribute__((ext_vector_type(4))) float;

// ---------------- Pass 1: streaming stats over x ----------------
// Per row n of batch b:  q = x_row . wq_ch ;  e = exp(q)
// Per-block partials (plain stores, no atomics/memset):
//   pS[b,blk,c] = sum e*x ; pX[b,blk,c] = sum x ; pZ[b,blk] = sum e
__global__ __launch_bounds__(256, 8) void psa_pass1(
    const float* __restrict__ x, const float* __restrict__ wq_ch,
    float* __restrict__ pS, float* __restrict__ pX, float* __restrict__ pZ)
{
    const int b    = blockIdx.x / BPB;
    const int blk  = blockIdx.x % BPB;
    const int tid  = threadIdx.x;
    const int l32  = tid & 31;      // lane within 32-lane row group
    const int slot = tid >> 5;      // 0..7

    const f4 wq = reinterpret_cast<const f4*>(wq_ch)[l32];

    float s0=0.f,s1=0.f,s2=0.f,s3=0.f;
    float a0=0.f,a1=0.f,a2=0.f,a3=0.f;
    float zacc=0.f;

    const float* xb = x + (size_t)b * (size_t)(HWN * CC);
    const int row0 = blk * ROWS;

    // 4 rows in flight per 32-lane slot (8 per wave)
    for (int i = slot; i < ROWS; i += 32) {
        const f4 x0 = reinterpret_cast<const f4*>(xb + (size_t)(row0 + i)      * CC)[l32];
        const f4 x1 = reinterpret_cast<const f4*>(xb + (size_t)(row0 + i + 8)  * CC)[l32];
        const f4 x2 = reinterpret_cast<const f4*>(xb + (size_t)(row0 + i + 16) * CC)[l32];
        const f4 x3 = reinterpret_cast<const f4*>(xb + (size_t)(row0 + i + 24) * CC)[l32];
        float p0 = x0.x*wq.x + x0.y*wq.y + x0.z*wq.z + x0.w*wq.w;
        float p1 = x1.x*wq.x + x1.y*wq.y + x1.z*wq.z + x1.w*wq.w;
        float p2 = x2.x*wq.x + x2.y*wq.y + x2.z*wq.z + x2.w*wq.w;
        float p3 = x3.x*wq.x + x3.y*wq.y + x3.z*wq.z + x3.w*wq.w;
        p0 += __shfl_xor(p0, 1);  p1 += __shfl_xor(p1, 1);
        p2 += __shfl_xor(p2, 1);  p3 += __shfl_xor(p3, 1);
        p0 += __shfl_xor(p0, 2);  p1 += __shfl_xor(p1, 2);
        p2 += __shfl_xor(p2, 2);  p3 += __shfl_xor(p3, 2);
        p0 += __shfl_xor(p0, 4);  p1 += __shfl_xor(p1, 4);
        p2 += __shfl_xor(p2, 4);  p3 += __shfl_xor(p3, 4);
        p0 += __shfl_xor(p0, 8);  p1 += __shfl_xor(p1, 8);
        p2 += __shfl_xor(p2, 8);  p3 += __shfl_xor(p3, 8);
        p0 += __shfl_xor(p0, 16); p1 += __shfl_xor(p1, 16);
        p2 += __shfl_xor(p2, 16); p3 += __shfl_xor(p3, 16);
        const float e0 = __expf(p0), e1 = __expf(p1);
        const float e2 = __expf(p2), e3 = __expf(p3);
        if (l32 == 0) zacc += (e0 + e1) + (e2 + e3);
        s0 += e0*x0.x + e1*x1.x + e2*x2.x + e3*x3.x;
        s1 += e0*x0.y + e1*x1.y + e2*x2.y + e3*x3.y;
        s2 += e0*x0.z + e1*x1.z + e2*x2.z + e3*x3.z;
        s3 += e0*x0.w + e1*x1.w + e2*x2.w + e3*x3.w;
        a0 += (x0.x + x1.x) + (x2.x + x3.x);
        a1 += (x0.y + x1.y) + (x2.y + x3.y);
        a2 += (x0.z + x1.z) + (x2.z + x3.z);
        a3 += (x0.w + x1.w) + (x2.w + x3.w);
    }

    __shared__ float Ssh[CC];
    __shared__ float Xsh[CC];
    __shared__ float zsh;
    if (tid < CC) { Ssh[tid] = 0.f; Xsh[tid] = 0.f; }
    if (tid == 0) zsh = 0.f;
    __syncthreads();

    const int cb = l32 * 4;
    atomicAdd(&Ssh[cb+0], s0); atomicAdd(&Ssh[cb+1], s1);
    atomicAdd(&Ssh[cb+2], s2); atomicAdd(&Ssh[cb+3], s3);
    atomicAdd(&Xsh[cb+0], a0); atomicAdd(&Xsh[cb+1], a1);
    atomicAdd(&Xsh[cb+2], a2); atomicAdd(&Xsh[cb+3], a3);
    if (l32 == 0) atomicAdd(&zsh, zacc);
    __syncthreads();

    const size_t base = (size_t)(b * BPB + blk) * CC;
    if (tid < CC) {
        pS[base + tid] = Ssh[tid];
        pX[base + tid] = Xsh[tid];
    }
    if (tid == 0) pZ[b * BPB + blk] = zsh;
}

// ---------------- Pass 2: replicated mid + streaming output ----------------
// Head (per block, redundant per batch -- partials are L2/L3-hot):
//   S,X = reduce 64 partials ; Z = reduce pZ
//   ctxh = (S @ wv_ch)/Z ; qsp = softmax((X @ wq_sp)/hw)
//   ctx = ctxh @ w_ch -> LN -> sigmoid -> mask_sh[128]
//   wf_sh = wv_sp @ qsp
// Body: out[b,n,c] = x[b,n,c] * (mask_sh[c] + sigmoid(x_row . wf_sh))
__global__ __launch_bounds__(256, 8) void psa_pass2(
    const float* __restrict__ x,
    const float* __restrict__ pS, const float* __restrict__ pX,
    const float* __restrict__ pZ,
    const float* __restrict__ wv_ch, const float* __restrict__ w_ch,
    const float* __restrict__ gamma, const float* __restrict__ beta,
    const float* __restrict__ wq_sp, const float* __restrict__ wv_sp,
    float* __restrict__ out)
{
    const int b    = blockIdx.x / BPB;
    const int blk  = blockIdx.x % BPB;
    const int tid  = threadIdx.x;
    const int l32  = tid & 31;
    const int slot = tid >> 5;

    __shared__ float Ssh[CC], Xsh[CC], ctxh[CH], qsp[CH];
    __shared__ __align__(16) float mask_sh[CC], wf_sh[CC];
    __shared__ float zsh, red2[2];

    // ---- mid head (threads 0..127 active; bit-identical across blocks) ----
    if (tid < CC) {
        const float* pSb = pS + (size_t)b * BPB * CC;
        const float* pXb = pX + (size_t)b * BPB * CC;
        float s = 0.f, a = 0.f;
        #pragma unroll
        for (int k = 0; k < BPB; ++k) {
            s += pSb[(size_t)k * CC + tid];
            a += pXb[(size_t)k * CC + tid];
        }
        Ssh[tid] = s; Xsh[tid] = a;
    }
    if (tid < 64) {   // wave 0 reduces Z over 64 partials
        float z = pZ[b * BPB + tid];
        z += __shfl_xor(z, 1); z += __shfl_xor(z, 2);  z += __shfl_xor(z, 4);
        z += __shfl_xor(z, 8); z += __shfl_xor(z, 16); z += __shfl_xor(z, 32);
        if (tid == 0) zsh = z;
    }
    __syncthreads();

    if (tid < CH) {
        float a = 0.f, aq = 0.f;
        #pragma unroll
        for (int c = 0; c < CC; ++c) {
            a  += Ssh[c] * wv_ch[c*CH + tid];
            aq += Xsh[c] * wq_sp[c*CH + tid];
        }
        ctxh[tid] = a / zsh;
        // spatial softmax over 64 (wave 0)
        float q = aq * (1.0f / (float)HWN);
        float m = q;
        m = fmaxf(m, __shfl_xor(m, 1));  m = fmaxf(m, __shfl_xor(m, 2));
        m = fmaxf(m, __shfl_xor(m, 4));  m = fmaxf(m, __shfl_xor(m, 8));
        m = fmaxf(m, __shfl_xor(m, 16)); m = fmaxf(m, __shfl_xor(m, 32));
        float e = __expf(q - m);
        float sum = e;
        sum += __shfl_xor(sum, 1);  sum += __shfl_xor(sum, 2);
        sum += __shfl_xor(sum, 4);  sum += __shfl_xor(sum, 8);
        sum += __shfl_xor(sum, 16); sum += __shfl_xor(sum, 32);
        qsp[tid] = e / sum;
    }
    __syncthreads();

    float ctx = 0.f;
    if (tid < CC) {
        #pragma unroll
        for (int d = 0; d < CH; ++d) ctx += ctxh[d] * w_ch[d*CC + tid];
    }
    {
        float r = (tid < CC) ? ctx : 0.f;
        r += __shfl_xor(r, 1);  r += __shfl_xor(r, 2);  r += __shfl_xor(r, 4);
        r += __shfl_xor(r, 8);  r += __shfl_xor(r, 16); r += __shfl_xor(r, 32);
        if ((tid & 63) == 0 && tid < CC) red2[tid >> 6] = r;
    }
    __syncthreads();
    const float mu = (red2[0] + red2[1]) * (1.0f / CC);
    __syncthreads();
    const float dc = (tid < CC) ? (ctx - mu) : 0.f;
    {
        float r = dc * dc;
        r += __shfl_xor(r, 1);  r += __shfl_xor(r, 2);  r += __shfl_xor(r, 4);
        r += __shfl_xor(r, 8);  r += __shfl_xor(r, 16); r += __shfl_xor(r, 32);
        if ((tid & 63) == 0 && tid < CC) red2[tid >> 6] = r;
    }
    __syncthreads();
    const float var = (red2[0] + red2[1]) * (1.0f / CC);

    if (tid < CC) {
        const float nrm = dc * rsqrtf(var + 1e-5f) * gamma[tid] + beta[tid];
        mask_sh[tid] = 1.0f / (1.0f + __expf(-nrm));
        float wacc = 0.f;
        #pragma unroll
        for (int d = 0; d < CH; ++d) wacc += wv_sp[tid*CH + d] * qsp[d];
        wf_sh[tid] = wacc;
    }
    __syncthreads();

    // ---- streaming body ----
    const f4 m4 = reinterpret_cast<const f4*>(mask_sh)[l32];
    const f4 w4 = reinterpret_cast<const f4*>(wf_sh)[l32];

    const float* xb = x   + (size_t)b * (size_t)(HWN * CC);
    float*       ob = out + (size_t)b * (size_t)(HWN * CC);
    const int row0 = blk * ROWS;

    for (int i = slot; i < ROWS; i += 32) {
        const size_t off0 = (size_t)(row0 + i)      * CC;
        const size_t off1 = (size_t)(row0 + i + 8)  * CC;
        const size_t off2 = (size_t)(row0 + i + 16) * CC;
        const size_t off3 = (size_t)(row0 + i + 24) * CC;
        const f4 x0 = reinterpret_cast<const f4*>(xb + off0)[l32];
        const f4 x1 = reinterpret_cast<const f4*>(xb + off1)[l32];
        const f4 x2 = reinterpret_cast<const f4*>(xb + off2)[l32];
        const f4 x3 = reinterpret_cast<const f4*>(xb + off3)[l32];
        float p0 = x0.x*w4.x + x0.y*w4.y + x0.z*w4.z + x0.w*w4.w;
        float p1 = x1.x*w4.x + x1.y*w4.y + x1.z*w4.z + x1.w*w4.w;
        float p2 = x2.x*w4.x + x2.y*w4.y + x2.z*w4.z + x2.w*w4.w;
        float p3 = x3.x*w4.x + x3.y*w4.y + x3.z*w4.z + x3.w*w4.w;
        p0 += __shfl_xor(p0, 1);  p1 += __shfl_xor(p1, 1);
        p2 += __shfl_xor(p2, 1);  p3 += __shfl_xor(p3, 1);
        p0 += __shfl_xor(p0, 2);  p1 += __shfl_xor(p1, 2);
        p2 += __shfl_xor(p2, 2);  p3 += __shfl_xor(p3, 2);
        p0 += __shfl_xor(p0, 4);  p1 += __shfl_xor(p1, 4);
        p2 += __shfl_xor(p2, 4);  p3 += __shfl_xor(p3, 4);
        p0 += __shfl_xor(p0, 8);  p1 += __shfl_xor(p1, 8);
        p2 += __shfl_xor(p2, 8);  p3 += __shfl_xor(p3, 8);
        p0 += __shfl_xor(p0, 16); p1 += __shfl_xor(p1, 16);
        p2 += __shfl_xor(p2, 16); p3 += __shfl_xor(p3, 16);
        const float g0 = 1.0f / (1.0f + __expf(-p0));
        const float g1 = 1.0f / (1.0f + __expf(-p1));
        const float g2 = 1.0f / (1.0f + __expf(-p2));
        const float g3 = 1.0f / (1.0f + __expf(-p3));
        f4 o0, o1, o2, o3;
        o0.x = x0.x*(m4.x+g0); o0.y = x0.y*(m4.y+g0); o0.z = x0.z*(m4.z+g0); o0.w = x0.w*(m4.w+g0);
        o1.x = x1.x*(m4.x+g1); o1.y = x1.y*(m4.y+g1); o1.z = x1.z*(m4.z+g1); o1.w = x1.w*(m4.w+g1);
        o2.x = x2.x*(m4.x+g2); o2.y = x2.y*(m4.y+g2); o2.z = x2.z*(m4.z+g2); o2.w = x2.w*(m4.w+g2);
        o3.x = x3.x*(m4.x+g3); o3.y = x3.y*(m4.y+g3); o3.z = x3.z*(m4.z+g3); o3.w = x3.w*(m4.w+g3);
        // non-temporal: keep the out stream from evicting x in cache
        __builtin_nontemporal_store(o0, reinterpret_cast<f4*>(ob + off0) + l32);
        __builtin_nontemporal_store(o1, reinterpret_cast<f4*>(ob + off1) + l32);
        __builtin_nontemporal_store(o2, reinterpret_cast<f4*>(ob + off2) + l32);
        __builtin_nontemporal_store(o3, reinterpret_cast<f4*>(ob + off3) + l32);
    }
}

extern "C" void kernel_launch(void* const* d_in, const int* in_sizes, int n_in,
                              void* d_out, int out_size, void* d_ws, size_t ws_size,
                              hipStream_t stream) {
    const float* x     = (const float*)d_in[0];
    const float* wq_ch = (const float*)d_in[1];
    const float* wv_ch = (const float*)d_in[2];
    const float* w_ch  = (const float*)d_in[3];
    const float* gamma = (const float*)d_in[4];
    const float* beta  = (const float*)d_in[5];
    const float* wq_sp = (const float*)d_in[6];
    const float* wv_sp = (const float*)d_in[7];
    float* out = (float*)d_out;

    // workspace (floats): pS[32*64*128] | pX[32*64*128] | pZ[32*64]
    float* ws = (float*)d_ws;
    float* pS = ws;
    float* pX = pS + (size_t)BSZ*BPB*CC;
    float* pZ = pX + (size_t)BSZ*BPB*CC;

    psa_pass1<<<BSZ*BPB, 256, 0, stream>>>(x, wq_ch, pS, pX, pZ);
    psa_pass2<<<BSZ*BPB, 256, 0, stream>>>(x, pS, pX, pZ, wv_ch, w_ch,
                                           gamma, beta, wq_sp, wv_sp, out);
}